// Round 22
// baseline (143.574 us; speedup 1.0000x reference)
//
#include <hip/hip_runtime.h>
#include <hip/hip_bf16.h>
#include <stdint.h>

typedef __bf16 bf16;
typedef __attribute__((ext_vector_type(8))) __bf16 bf16x8;
typedef __attribute__((ext_vector_type(4))) __bf16 bf16x4;
typedef __attribute__((ext_vector_type(4))) float f32x4;

constexpr int Bn = 4, Tn = 2048, Cn = 1024, Hn = 16, HD = 64;
constexpr int Mn = Bn * Tn; // 8192

__device__ __forceinline__ void gl_lds16(const void* g, void* l) {
  __builtin_amdgcn_global_load_lds(
      (const __attribute__((address_space(1))) void*)g,
      (__attribute__((address_space(3))) void*)l, 16u, 0, 0u);
}

// ---- fused prep: blocks [0,4096): x fp32->bf16; [4096,8192): W transpose ----
__global__ __launch_bounds__(256) void k_prep(const float* __restrict__ x,
                                              bf16* __restrict__ xb,
                                              const float* __restrict__ W0,
                                              const float* __restrict__ W1,
                                              const float* __restrict__ W2,
                                              const float* __restrict__ W3,
                                              bf16* __restrict__ WT) {
  __shared__ float tile[32][33];
  int b = blockIdx.x;
  if (b < 4096) {
    int i = (b * 256 + threadIdx.x) * 8;
    float4 a = *(const float4*)(x + i);
    float4 c = *(const float4*)(x + i + 4);
    bf16x8 v;
    v[0] = (bf16)a.x; v[1] = (bf16)a.y; v[2] = (bf16)a.z; v[3] = (bf16)a.w;
    v[4] = (bf16)c.x; v[5] = (bf16)c.y; v[6] = (bf16)c.z; v[7] = (bf16)c.w;
    *(bf16x8*)(xb + i) = v;
    return;
  }
  b -= 4096;
  const int z = b >> 10, rem = b & 1023;
  const int bx = rem & 31, by = rem >> 5;
  const float* W = (z == 0) ? W0 : (z == 1) ? W1 : (z == 2) ? W2 : W3;
  bf16* out = WT + (size_t)z * Cn * Cn;
  int tx = threadIdx.x & 31, ty = threadIdx.x >> 5;  // 32 x 8
  int gx = bx * 32 + tx;   // n
  int gy = by * 32;        // k
#pragma unroll
  for (int j = 0; j < 32; j += 8)
    tile[ty + j][tx] = W[(size_t)(gy + ty + j) * Cn + gx];
  __syncthreads();
  int ox = by * 32 + tx;   // k
  int oy = bx * 32;        // n
#pragma unroll
  for (int j = 0; j < 32; j += 8)
    out[(size_t)(oy + ty + j) * Cn + ox] = (bf16)tile[tx][ty + j];
}

// ---- 2-phase counted-vmcnt GEMM core (128x128, BK=64, 8 waves) -----------
// [converged core: 60-64us qkv8, MfmaUtil ~33%, VGPR 52, no spill]
// 64 KiB LDS (2 blocks/CU). Per-wave 64x32 (wm{0,1} x wn{0..3}), acc[4][2].
// Per K-tile: P0 {stage 4 gl_lds of j+1; vmcnt(4); barrier; read B(4)+A01;
// 8 MFMA} P1 {read A23; 8 MFMA; barrier}. Counted vmcnt only.
#define GEMM_CORE(ACC)                                                      \
  const int t = threadIdx.x, l = t & 63, w = t >> 6;                        \
  const int g = l >> 4, q16 = l & 15;                                       \
  const int wm = w >> 2, wn = w & 3;                                        \
  const int xm = (q16 & 7) << 4;                                            \
  const int qkB0 = q16 * 128 + ((g * 16) ^ xm);                             \
  const int qkB1 = q16 * 128 + ((64 + g * 16) ^ xm);                        \
  const int srow = t >> 3;                                                  \
  const int sseg = (t & 7) ^ (srow & 7);                                    \
  const bf16* aP0 = A + (size_t)(m0 + srow) * 1024 + sseg * 8;              \
  const bf16* aP1 = aP0 + 65536;                                            \
  const bf16* bP0 = BT + (size_t)(n0 + srow) * 1024 + sseg * 8;             \
  const bf16* bP1 = bP0 + 65536;                                            \
  f32x4 ACC[4][2] = {};                                                     \
  gl_lds16(aP0, sm + w * 1024);                                             \
  gl_lds16(aP1, sm + 8192 + w * 1024);                                      \
  gl_lds16(bP0, sm + 16384 + w * 1024);                                     \
  gl_lds16(bP1, sm + 24576 + w * 1024);                                     \
  _Pragma("unroll")                                                         \
  for (int j = 0; j < 16; ++j) {                                            \
    const int BK_ = (j & 1) ? 32768 : 0;                                    \
    const int NB_ = 32768 - BK_;                                            \
    const bool more = j < 15;                                               \
    if (more) {                                                             \
      gl_lds16(aP0 + (j + 1) * 64, sm + NB_ + w * 1024);                    \
      gl_lds16(aP1 + (j + 1) * 64, sm + NB_ + 8192 + w * 1024);             \
      gl_lds16(bP0 + (j + 1) * 64, sm + NB_ + 16384 + w * 1024);            \
      gl_lds16(bP1 + (j + 1) * 64, sm + NB_ + 24576 + w * 1024);            \
      asm volatile("s_waitcnt vmcnt(4)" ::: "memory");                      \
    } else {                                                                \
      asm volatile("s_waitcnt vmcnt(0)" ::: "memory");                      \
    }                                                                       \
    __builtin_amdgcn_sched_barrier(0);                                      \
    __builtin_amdgcn_s_barrier();                                           \
    bf16x8 bfr[2][2], af0[2], af1[2];                                       \
    _Pragma("unroll") for (int ni = 0; ni < 2; ++ni) {                      \
      bfr[ni][0] = *(const bf16x8*)(sm + BK_ + 16384 + wn * 4096 +          \
                                    ni * 2048 + qkB0);                      \
      bfr[ni][1] = *(const bf16x8*)(sm + BK_ + 16384 + wn * 4096 +          \
                                    ni * 2048 + qkB1);                      \
    }                                                                       \
    af0[0] = *(const bf16x8*)(sm + BK_ + wm * 8192 + qkB0);                 \
    af0[1] = *(const bf16x8*)(sm + BK_ + wm * 8192 + qkB1);                 \
    af1[0] = *(const bf16x8*)(sm + BK_ + wm * 8192 + 2048 + qkB0);          \
    af1[1] = *(const bf16x8*)(sm + BK_ + wm * 8192 + 2048 + qkB1);          \
    __builtin_amdgcn_s_setprio(1);                                          \
    _Pragma("unroll") for (int ni = 0; ni < 2; ++ni) {                      \
      ACC[0][ni] = __builtin_amdgcn_mfma_f32_16x16x32_bf16(                 \
          af0[0], bfr[ni][0], ACC[0][ni], 0, 0, 0);                         \
      ACC[0][ni] = __builtin_amdgcn_mfma_f32_16x16x32_bf16(                 \
          af0[1], bfr[ni][1], ACC[0][ni], 0, 0, 0);                         \
      ACC[1][ni] = __builtin_amdgcn_mfma_f32_16x16x32_bf16(                 \
          af1[0], bfr[ni][0], ACC[1][ni], 0, 0, 0);                         \
      ACC[1][ni] = __builtin_amdgcn_mfma_f32_16x16x32_bf16(                 \
          af1[1], bfr[ni][1], ACC[1][ni], 0, 0, 0);                         \
    }                                                                       \
    __builtin_amdgcn_s_setprio(0);                                          \
    af0[0] = *(const bf16x8*)(sm + BK_ + wm * 8192 + 4096 + qkB0);          \
    af0[1] = *(const bf16x8*)(sm + BK_ + wm * 8192 + 4096 + qkB1);          \
    af1[0] = *(const bf16x8*)(sm + BK_ + wm * 8192 + 6144 + qkB0);          \
    af1[1] = *(const bf16x8*)(sm + BK_ + wm * 8192 + 6144 + qkB1);          \
    __builtin_amdgcn_s_setprio(1);                                          \
    _Pragma("unroll") for (int ni = 0; ni < 2; ++ni) {                      \
      ACC[2][ni] = __builtin_amdgcn_mfma_f32_16x16x32_bf16(                 \
          af0[0], bfr[ni][0], ACC[2][ni], 0, 0, 0);                         \
      ACC[2][ni] = __builtin_amdgcn_mfma_f32_16x16x32_bf16(                 \
          af0[1], bfr[ni][1], ACC[2][ni], 0, 0, 0);                         \
      ACC[3][ni] = __builtin_amdgcn_mfma_f32_16x16x32_bf16(                 \
          af1[0], bfr[ni][0], ACC[3][ni], 0, 0, 0);                         \
      ACC[3][ni] = __builtin_amdgcn_mfma_f32_16x16x32_bf16(                 \
          af1[1], bfr[ni][1], ACC[3][ni], 0, 0, 0);                         \
    }                                                                       \
    __builtin_amdgcn_s_setprio(0);                                          \
    __builtin_amdgcn_s_barrier();                                           \
  }

// -------- fused QKV GEMM: N = 3072 (Wq|Wk|Wv stacked in WT) ---------------
// XCD n-strip swizzle (proven -4us r21): XCD k8 owns n-tiles {3k8..3k8+2}
// x all 64 m-panels -> per-XCD B-slice 768 KB L2-resident.
__global__ __launch_bounds__(512, 2) void k_gemm_qkv8(
    const bf16* __restrict__ A, const bf16* __restrict__ BT,
    const float* __restrict__ bq, const float* __restrict__ bk,
    const float* __restrict__ bv, bf16* __restrict__ out, float qscale) {
  __shared__ __align__(16) char sm[65536];
  const int b0 = blockIdx.x;
  const int k8 = b0 & 7, j = b0 >> 3;
  const int n0 = (3 * k8 + j % 3) * 128, m0 = (j / 3) * 128;
  GEMM_CORE(acc)
#pragma unroll
  for (int ni = 0; ni < 2; ++ni) {
    int colBase = n0 + wn * 32 + ni * 16;
    int which = colBase >> 10;  // 0=Q 1=K 2=V
    const float* bp = (which == 0) ? bq : (which == 1) ? bk : bv;
    float scl = (which == 0) ? qscale : 1.0f;
    float bval = bp[(colBase & 1023) + q16];
    int hh = (colBase >> 6) & 15;
    int dd = (colBase & 63) + q16;
    size_t obase = (size_t)which * 8388608 + (size_t)hh * (Tn * HD) + dd;
#pragma unroll
    for (int mi = 0; mi < 4; ++mi) {
#pragma unroll
      for (int r = 0; r < 4; ++r) {
        int row = m0 + wm * 64 + mi * 16 + g * 4 + r;
        int bb = row >> 11, tt = row & 2047;
        out[obase + ((size_t)bb * Hn * Tn + tt) * HD] =
            (bf16)((acc[mi][ni][r] + bval) * scl);
      }
    }
  }
}

// -------- output projection GEMM: out fp32 flat [M][C], same core ---------
// m-strip kept: whole 512-block grid co-resident; per-XCD footprint
// A 2MB + B 2MB = 4MB (n-strip would demand A 16MB co-resident).
__global__ __launch_bounds__(512, 2) void k_gemm_o8(
    const bf16* __restrict__ A, const bf16* __restrict__ BT,
    const float* __restrict__ bias, float* __restrict__ out) {
  __shared__ __align__(16) char sm[65536];
  const int b0 = blockIdx.x;
  const int blk = (b0 & 7) * 64 + (b0 >> 3);
  const int m0 = (blk >> 3) * 128, n0 = (blk & 7) * 128;
  GEMM_CORE(acc)
#pragma unroll
  for (int ni = 0; ni < 2; ++ni) {
    int col = n0 + wn * 32 + ni * 16 + q16;
    float bv = bias[col];
#pragma unroll
    for (int mi = 0; mi < 4; ++mi) {
#pragma unroll
      for (int r = 0; r < 4; ++r) {
        int row = m0 + wm * 64 + mi * 16 + g * 4 + r;
        out[(size_t)row * Cn + col] = acc[mi][ni][r] + bv;
      }
    }
  }
}

// ---------------- flash attention (causal), 8-wave QBLK=128 ----------------
// + T13 defer-max. qtile mapping: balanced nibble-LUT 0x5410672398DCABEF --
// all 1024 blocks are co-resident (4/CU), so under round-robin dispatch CU c
// gets qt_idx {a,a+4,a+8,a+12}; old map 15-idx gave per-CU work sums
// {80,72,64,56} nt-iters (30% tail idle); LUT makes every class sum 30
// (68 iters/CU). Bijection on [0,16) -> correctness unaffected.
__global__ __launch_bounds__(512, 4) void k_attn(const bf16* __restrict__ Q,
                                                 const bf16* __restrict__ K,
                                                 const bf16* __restrict__ V,
                                                 bf16* __restrict__ Y) {
  __shared__ __align__(16) char smem[32768];
  const int t = threadIdx.x, w = t >> 6, l = t & 63;
  const int g = l >> 4, q16 = l & 15;
  const int wg = blockIdx.x;
  const int bh = wg & 63;                      // low bits -> XCD pinning
  const int qtile = (int)((0x5410672398DCABEFull >> ((wg >> 6) * 4)) & 15);
  const size_t base = (size_t)bh * Tn * HD;
  const bf16* Qh = Q + base;
  const bf16* Vh = V + base;
  const int qg = qtile * 128 + w * 16 + q16;   // this lane's q row

  bf16x8 aq[2];
#pragma unroll
  for (int kc = 0; kc < 2; ++kc)
    aq[kc] = *(const bf16x8*)(Qh + (size_t)qg * HD + kc * 32 + g * 8);

  const int xm = (q16 & 7) << 4;
  const int qkB0 = q16 * 128 + ((g * 16) ^ xm);
  const int qkB1 = q16 * 128 + ((64 + g * 16) ^ xm);
  const int innerL = (l >> 5) * 64 + ((l & 15) >> 2) * 16 +
                     (((l >> 4) & 1) * 4 + (l & 3)) * 2;
  int stb[8];
#pragma unroll
  for (int j = 0; j < 8; ++j)
    stb[j] = w * 1024 + j * 128 + (innerL ^ (j << 4));

  const int krow = w * 8 + (l >> 3);
  const int kseg = (l & 7) ^ (krow & 7);
  const bf16* kP = K + base + (size_t)krow * HD + kseg * 8;
  const bf16* vP = Vh + (size_t)l * HD + w * 8;

  f32x4 yacc[4] = {};
  float m_ = -1e30f, l_ = 0.f;
  const int nt = 2 * qtile + 2;
  const int it_mask = 2 * qtile + (w >= 4 ? 1 : 0);
  const int diag = (w & 3) * 16 + q16;

#define STAGE_K(KBUF)                           \
  {                                             \
    gl_lds16(kP, smem + (KBUF) + w * 1024);     \
    kP += 4096;                                 \
  }
#define WRITE_V(VBUF, a0)                               \
  {                                                     \
    _Pragma("unroll") for (int j = 0; j < 8; ++j)       \
      *(bf16*)(smem + (VBUF) + stb[j]) = a0[j];         \
  }
#define COMPUTE(KBUF, VBUF, DOMASK)                                          \
  {                                                                          \
    f32x4 s[4] = {};                                                         \
    __builtin_amdgcn_s_setprio(1);                                           \
    _Pragma("unroll") for (int nj = 0; nj < 4; ++nj) {                       \
      bf16x8 ak0 = *(const bf16x8*)(smem + (KBUF) + qkB0 + nj * 2048);       \
      s[nj] = __builtin_amdgcn_mfma_f32_16x16x32_bf16(ak0, aq[0], s[nj], 0, 0, 0); \
      bf16x8 ak1 = *(const bf16x8*)(smem + (KBUF) + qkB1 + nj * 2048);       \
      s[nj] = __builtin_amdgcn_mfma_f32_16x16x32_bf16(ak1, aq[1], s[nj], 0, 0, 0); \
    }                                                                        \
    __builtin_amdgcn_s_setprio(0);                                           \
    if (DOMASK) {                                                            \
      _Pragma("unroll") for (int nj = 0; nj < 4; ++nj)                       \
        _Pragma("unroll") for (int r = 0; r < 4; ++r)                        \
          if (nj * 16 + g * 4 + r > diag) s[nj][r] = -1e30f;                 \
    }                                                                        \
    float mx = fmaxf(fmaxf(fmaxf(s[0][0], s[0][1]), fmaxf(s[0][2], s[0][3])),\
                     fmaxf(fmaxf(s[1][0], s[1][1]), fmaxf(s[1][2], s[1][3])));\
    mx = fmaxf(mx, fmaxf(fmaxf(fmaxf(s[2][0], s[2][1]), fmaxf(s[2][2], s[2][3])),\
                         fmaxf(fmaxf(s[3][0], s[3][1]), fmaxf(s[3][2], s[3][3]))));\
    mx = fmaxf(mx, __shfl_xor(mx, 16));                                      \
    mx = fmaxf(mx, __shfl_xor(mx, 32));                                      \
    if (!__all(mx <= m_ + 8.f)) { /* T13 defer-max */                        \
      float mn = fmaxf(m_, mx);                                              \
      float fac = __builtin_amdgcn_exp2f(m_ - mn);                           \
      m_ = mn;                                                               \
      l_ *= fac;                                                             \
      _Pragma("unroll") for (int ni = 0; ni < 4; ++ni)                       \
        _Pragma("unroll") for (int r = 0; r < 4; ++r) yacc[ni][r] *= fac;    \
    }                                                                        \
    float rs = 0.f;                                                          \
    _Pragma("unroll") for (int nj = 0; nj < 4; ++nj)                         \
      _Pragma("unroll") for (int r = 0; r < 4; ++r) {                        \
        float pv = __builtin_amdgcn_exp2f(s[nj][r] - m_);                    \
        s[nj][r] = pv;                                                       \
        rs += pv;                                                            \
      }                                                                      \
    rs += __shfl_xor(rs, 16);                                                \
    rs += __shfl_xor(rs, 32);                                                \
    l_ += rs;                                                                \
    __builtin_amdgcn_s_setprio(1);                                           \
    _Pragma("unroll") for (int vkc = 0; vkc < 2; ++vkc) {                    \
      bf16x8 pb;                                                             \
      _Pragma("unroll") for (int j = 0; j < 4; ++j) {                        \
        pb[j] = (bf16)s[2 * vkc][j];                                         \
        pb[4 + j] = (bf16)s[2 * vkc + 1][j];                                 \
      }                                                                      \
      int vb = (vkc == 0) ? qkB0 : qkB1;                                     \
      _Pragma("unroll") for (int ni = 0; ni < 4; ++ni) {                     \
        bf16x8 va = *(const bf16x8*)(smem + (VBUF) + vb + ni * 2048);        \
        yacc[ni] = __builtin_amdgcn_mfma_f32_16x16x32_bf16(va, pb, yacc[ni], 0, 0, 0); \
      }                                                                      \
    }                                                                        \
    __builtin_amdgcn_s_setprio(0);                                           \
  }

  STAGE_K(0);
  {
    bf16x8 a0 = *(const bf16x8*)vP;
    vP += 4096;
    WRITE_V(16384, a0);
  }

  int it = 0;
  for (;;) {
    __syncthreads();
    bool more = (it + 1) < nt;
    bf16x8 a0;
    if (more) {
      STAGE_K(8192);
      a0 = *(const bf16x8*)vP;
      vP += 4096;
    }
    if (it <= it_mask) COMPUTE(0, 16384, it == it_mask);
    if (more) WRITE_V(24576, a0);
    if (++it >= nt) break;

    __syncthreads();
    more = (it + 1) < nt;
    if (more) {
      STAGE_K(0);
      a0 = *(const bf16x8*)vP;
      vP += 4096;
    }
    if (it <= it_mask) COMPUTE(8192, 24576, it == it_mask);
    if (more) WRITE_V(16384, a0);
    if (++it >= nt) break;
  }
#undef STAGE_K
#undef WRITE_V
#undef COMPUTE

  const int hh = bh & 15, bb = bh >> 4;
  float inv = 1.f / l_;
#pragma unroll
  for (int ni = 0; ni < 4; ++ni) {
    bf16x4 o;
#pragma unroll
    for (int r = 0; r < 4; ++r) o[r] = (bf16)(yacc[ni][r] * inv);
    int d0 = ni * 16 + g * 4;
    *(bf16x4*)&Y[(size_t)(bb * Tn + qg) * Cn + hh * HD + d0] = o;
  }
}

extern "C" void kernel_launch(void* const* d_in, const int* in_sizes, int n_in,
                              void* d_out, int out_size, void* d_ws,
                              size_t ws_size, hipStream_t stream) {
  const float* x  = (const float*)d_in[0];
  const float* Wq = (const float*)d_in[1];
  const float* bq = (const float*)d_in[2];
  const float* Wk = (const float*)d_in[3];
  const float* bk = (const float*)d_in[4];
  const float* Wv = (const float*)d_in[5];
  const float* bv = (const float*)d_in[6];
  const float* Wo = (const float*)d_in[7];
  const float* bo = (const float*)d_in[8];
  char* ws = (char*)d_ws;
  bf16* xb = (bf16*)ws;                          // 16MB, reused as y
  bf16* WT = (bf16*)(ws + (size_t)(16 << 20));   // 8MB (4 x 1M elems)
  bf16* Qh = (bf16*)(ws + (size_t)(24 << 20));   // 16MB (K,V follow)
  bf16* Kh = (bf16*)(ws + (size_t)(40 << 20));
  bf16* Vh = (bf16*)(ws + (size_t)(56 << 20));
  float* out = (float*)d_out;                    // reference output is fp32

  const float QSCALE = 0.125f * 1.44269504088896f;  // 1/sqrt(64) * log2(e)

  k_prep<<<8192, 256, 0, stream>>>(x, xb, Wq, Wk, Wv, Wo, WT);
  k_gemm_qkv8<<<1536, 512, 0, stream>>>(xb, WT, bq, bk, bv, Qh, QSCALE);
  k_attn<<<1024, 512, 0, stream>>>(Qh, Kh, Vh, xb);
  k_gemm_o8<<<512, 512, 0, stream>>>(xb, WT + (3u << 20), bo, out);
}

// Round 23
// 140.188 us; speedup vs baseline: 1.0242x; 1.0242x over previous
//
#include <hip/hip_runtime.h>
#include <hip/hip_bf16.h>
#include <stdint.h>

typedef __bf16 bf16;
typedef __attribute__((ext_vector_type(8))) __bf16 bf16x8;
typedef __attribute__((ext_vector_type(4))) __bf16 bf16x4;
typedef __attribute__((ext_vector_type(4))) float f32x4;

constexpr int Bn = 4, Tn = 2048, Cn = 1024, Hn = 16, HD = 64;
constexpr int Mn = Bn * Tn; // 8192

__device__ __forceinline__ void gl_lds16(const void* g, void* l) {
  __builtin_amdgcn_global_load_lds(
      (const __attribute__((address_space(1))) void*)g,
      (__attribute__((address_space(3))) void*)l, 16u, 0, 0u);
}

// ---- fused prep: blocks [0,4096): x fp32->bf16; [4096,8192): W transpose ----
__global__ __launch_bounds__(256) void k_prep(const float* __restrict__ x,
                                              bf16* __restrict__ xb,
                                              const float* __restrict__ W0,
                                              const float* __restrict__ W1,
                                              const float* __restrict__ W2,
                                              const float* __restrict__ W3,
                                              bf16* __restrict__ WT) {
  __shared__ float tile[32][33];
  int b = blockIdx.x;
  if (b < 4096) {
    int i = (b * 256 + threadIdx.x) * 8;
    float4 a = *(const float4*)(x + i);
    float4 c = *(const float4*)(x + i + 4);
    bf16x8 v;
    v[0] = (bf16)a.x; v[1] = (bf16)a.y; v[2] = (bf16)a.z; v[3] = (bf16)a.w;
    v[4] = (bf16)c.x; v[5] = (bf16)c.y; v[6] = (bf16)c.z; v[7] = (bf16)c.w;
    *(bf16x8*)(xb + i) = v;
    return;
  }
  b -= 4096;
  const int z = b >> 10, rem = b & 1023;
  const int bx = rem & 31, by = rem >> 5;
  const float* W = (z == 0) ? W0 : (z == 1) ? W1 : (z == 2) ? W2 : W3;
  bf16* out = WT + (size_t)z * Cn * Cn;
  int tx = threadIdx.x & 31, ty = threadIdx.x >> 5;  // 32 x 8
  int gx = bx * 32 + tx;   // n
  int gy = by * 32;        // k
#pragma unroll
  for (int j = 0; j < 32; j += 8)
    tile[ty + j][tx] = W[(size_t)(gy + ty + j) * Cn + gx];
  __syncthreads();
  int ox = by * 32 + tx;   // k
  int oy = bx * 32;        // n
#pragma unroll
  for (int j = 0; j < 32; j += 8)
    out[(size_t)(oy + ty + j) * Cn + ox] = (bf16)tile[tx][ty + j];
}

// ---- 2-phase counted-vmcnt GEMM core (128x128, BK=64, 8 waves) -----------
// [converged core: 60-64us qkv8, MfmaUtil ~33%, VGPR 52, no spill]
// 64 KiB LDS (2 blocks/CU). Per-wave 64x32 (wm{0,1} x wn{0..3}), acc[4][2].
// Per K-tile: P0 {stage 4 gl_lds of j+1; vmcnt(4); barrier; read B(4)+A01;
// 8 MFMA} P1 {read A23; 8 MFMA; barrier}. Counted vmcnt only.
#define GEMM_CORE(ACC)                                                      \
  const int t = threadIdx.x, l = t & 63, w = t >> 6;                        \
  const int g = l >> 4, q16 = l & 15;                                       \
  const int wm = w >> 2, wn = w & 3;                                        \
  const int xm = (q16 & 7) << 4;                                            \
  const int qkB0 = q16 * 128 + ((g * 16) ^ xm);                             \
  const int qkB1 = q16 * 128 + ((64 + g * 16) ^ xm);                        \
  const int srow = t >> 3;                                                  \
  const int sseg = (t & 7) ^ (srow & 7);                                    \
  const bf16* aP0 = A + (size_t)(m0 + srow) * 1024 + sseg * 8;              \
  const bf16* aP1 = aP0 + 65536;                                            \
  const bf16* bP0 = BT + (size_t)(n0 + srow) * 1024 + sseg * 8;             \
  const bf16* bP1 = bP0 + 65536;                                            \
  f32x4 ACC[4][2] = {};                                                     \
  gl_lds16(aP0, sm + w * 1024);                                             \
  gl_lds16(aP1, sm + 8192 + w * 1024);                                      \
  gl_lds16(bP0, sm + 16384 + w * 1024);                                     \
  gl_lds16(bP1, sm + 24576 + w * 1024);                                     \
  _Pragma("unroll")                                                         \
  for (int j = 0; j < 16; ++j) {                                            \
    const int BK_ = (j & 1) ? 32768 : 0;                                    \
    const int NB_ = 32768 - BK_;                                            \
    const bool more = j < 15;                                               \
    if (more) {                                                             \
      gl_lds16(aP0 + (j + 1) * 64, sm + NB_ + w * 1024);                    \
      gl_lds16(aP1 + (j + 1) * 64, sm + NB_ + 8192 + w * 1024);             \
      gl_lds16(bP0 + (j + 1) * 64, sm + NB_ + 16384 + w * 1024);            \
      gl_lds16(bP1 + (j + 1) * 64, sm + NB_ + 24576 + w * 1024);            \
      asm volatile("s_waitcnt vmcnt(4)" ::: "memory");                      \
    } else {                                                                \
      asm volatile("s_waitcnt vmcnt(0)" ::: "memory");                      \
    }                                                                       \
    __builtin_amdgcn_sched_barrier(0);                                      \
    __builtin_amdgcn_s_barrier();                                           \
    bf16x8 bfr[2][2], af0[2], af1[2];                                       \
    _Pragma("unroll") for (int ni = 0; ni < 2; ++ni) {                      \
      bfr[ni][0] = *(const bf16x8*)(sm + BK_ + 16384 + wn * 4096 +          \
                                    ni * 2048 + qkB0);                      \
      bfr[ni][1] = *(const bf16x8*)(sm + BK_ + 16384 + wn * 4096 +          \
                                    ni * 2048 + qkB1);                      \
    }                                                                       \
    af0[0] = *(const bf16x8*)(sm + BK_ + wm * 8192 + qkB0);                 \
    af0[1] = *(const bf16x8*)(sm + BK_ + wm * 8192 + qkB1);                 \
    af1[0] = *(const bf16x8*)(sm + BK_ + wm * 8192 + 2048 + qkB0);          \
    af1[1] = *(const bf16x8*)(sm + BK_ + wm * 8192 + 2048 + qkB1);          \
    __builtin_amdgcn_s_setprio(1);                                          \
    _Pragma("unroll") for (int ni = 0; ni < 2; ++ni) {                      \
      ACC[0][ni] = __builtin_amdgcn_mfma_f32_16x16x32_bf16(                 \
          af0[0], bfr[ni][0], ACC[0][ni], 0, 0, 0);                         \
      ACC[0][ni] = __builtin_amdgcn_mfma_f32_16x16x32_bf16(                 \
          af0[1], bfr[ni][1], ACC[0][ni], 0, 0, 0);                         \
      ACC[1][ni] = __builtin_amdgcn_mfma_f32_16x16x32_bf16(                 \
          af1[0], bfr[ni][0], ACC[1][ni], 0, 0, 0);                         \
      ACC[1][ni] = __builtin_amdgcn_mfma_f32_16x16x32_bf16(                 \
          af1[1], bfr[ni][1], ACC[1][ni], 0, 0, 0);                         \
    }                                                                       \
    __builtin_amdgcn_s_setprio(0);                                          \
    af0[0] = *(const bf16x8*)(sm + BK_ + wm * 8192 + 4096 + qkB0);          \
    af0[1] = *(const bf16x8*)(sm + BK_ + wm * 8192 + 4096 + qkB1);          \
    af1[0] = *(const bf16x8*)(sm + BK_ + wm * 8192 + 6144 + qkB0);          \
    af1[1] = *(const bf16x8*)(sm + BK_ + wm * 8192 + 6144 + qkB1);          \
    __builtin_amdgcn_s_setprio(1);                                          \
    _Pragma("unroll") for (int ni = 0; ni < 2; ++ni) {                      \
      ACC[2][ni] = __builtin_amdgcn_mfma_f32_16x16x32_bf16(                 \
          af0[0], bfr[ni][0], ACC[2][ni], 0, 0, 0);                         \
      ACC[2][ni] = __builtin_amdgcn_mfma_f32_16x16x32_bf16(                 \
          af0[1], bfr[ni][1], ACC[2][ni], 0, 0, 0);                         \
      ACC[3][ni] = __builtin_amdgcn_mfma_f32_16x16x32_bf16(                 \
          af1[0], bfr[ni][0], ACC[3][ni], 0, 0, 0);                         \
      ACC[3][ni] = __builtin_amdgcn_mfma_f32_16x16x32_bf16(                 \
          af1[1], bfr[ni][1], ACC[3][ni], 0, 0, 0);                         \
    }                                                                       \
    __builtin_amdgcn_s_setprio(0);                                          \
    __builtin_amdgcn_s_barrier();                                           \
  }

// -------- fused QKV GEMM: N = 3072 (Wq|Wk|Wv stacked in WT) ---------------
// XCD n-strip swizzle (proven -4us r21): XCD k8 owns n-tiles {3k8..3k8+2}
// x all 64 m-panels -> per-XCD B-slice 768 KB L2-resident.
__global__ __launch_bounds__(512, 2) void k_gemm_qkv8(
    const bf16* __restrict__ A, const bf16* __restrict__ BT,
    const float* __restrict__ bq, const float* __restrict__ bk,
    const float* __restrict__ bv, bf16* __restrict__ out, float qscale) {
  __shared__ __align__(16) char sm[65536];
  const int b0 = blockIdx.x;
  const int k8 = b0 & 7, j = b0 >> 3;
  const int n0 = (3 * k8 + j % 3) * 128, m0 = (j / 3) * 128;
  GEMM_CORE(acc)
#pragma unroll
  for (int ni = 0; ni < 2; ++ni) {
    int colBase = n0 + wn * 32 + ni * 16;
    int which = colBase >> 10;  // 0=Q 1=K 2=V
    const float* bp = (which == 0) ? bq : (which == 1) ? bk : bv;
    float scl = (which == 0) ? qscale : 1.0f;
    float bval = bp[(colBase & 1023) + q16];
    int hh = (colBase >> 6) & 15;
    int dd = (colBase & 63) + q16;
    size_t obase = (size_t)which * 8388608 + (size_t)hh * (Tn * HD) + dd;
#pragma unroll
    for (int mi = 0; mi < 4; ++mi) {
#pragma unroll
      for (int r = 0; r < 4; ++r) {
        int row = m0 + wm * 64 + mi * 16 + g * 4 + r;
        int bb = row >> 11, tt = row & 2047;
        out[obase + ((size_t)bb * Hn * Tn + tt) * HD] =
            (bf16)((acc[mi][ni][r] + bval) * scl);
      }
    }
  }
}

// -------- output projection GEMM: out fp32 flat [M][C], same core ---------
__global__ __launch_bounds__(512, 2) void k_gemm_o8(
    const bf16* __restrict__ A, const bf16* __restrict__ BT,
    const float* __restrict__ bias, float* __restrict__ out) {
  __shared__ __align__(16) char sm[65536];
  const int b0 = blockIdx.x;
  const int blk = (b0 & 7) * 64 + (b0 >> 3);
  const int m0 = (blk >> 3) * 128, n0 = (blk & 7) * 128;
  GEMM_CORE(acc)
#pragma unroll
  for (int ni = 0; ni < 2; ++ni) {
    int col = n0 + wn * 32 + ni * 16 + q16;
    float bv = bias[col];
#pragma unroll
    for (int mi = 0; mi < 4; ++mi) {
#pragma unroll
      for (int r = 0; r < 4; ++r) {
        int row = m0 + wm * 64 + mi * 16 + g * 4 + r;
        out[(size_t)row * Cn + col] = acc[mi][ni][r] + bv;
      }
    }
  }
}

// ---------------- flash attention (causal), 8-wave QBLK=128 ----------------
// + T13 defer-max. qtile = 15 - idx: heavy-tiles-FIRST (LPT). r22 falsified
// the all-co-resident model (Occupancy ~47% => ~2 blocks/CU, dynamic
// dispatch); under dynamic scheduling longest-first is near-optimal and the
// balanced-LUT variant cost +11us. Keep LPT.
__global__ __launch_bounds__(512, 4) void k_attn(const bf16* __restrict__ Q,
                                                 const bf16* __restrict__ K,
                                                 const bf16* __restrict__ V,
                                                 bf16* __restrict__ Y) {
  __shared__ __align__(16) char smem[32768];
  const int t = threadIdx.x, w = t >> 6, l = t & 63;
  const int g = l >> 4, q16 = l & 15;
  const int wg = blockIdx.x;
  const int bh = wg & 63;                      // low bits -> XCD pinning
  const int qtile = 15 - (wg >> 6);            // heavy tiles first (LPT)
  const size_t base = (size_t)bh * Tn * HD;
  const bf16* Qh = Q + base;
  const bf16* Vh = V + base;
  const int qg = qtile * 128 + w * 16 + q16;   // this lane's q row

  bf16x8 aq[2];
#pragma unroll
  for (int kc = 0; kc < 2; ++kc)
    aq[kc] = *(const bf16x8*)(Qh + (size_t)qg * HD + kc * 32 + g * 8);

  const int xm = (q16 & 7) << 4;
  const int qkB0 = q16 * 128 + ((g * 16) ^ xm);
  const int qkB1 = q16 * 128 + ((64 + g * 16) ^ xm);
  const int innerL = (l >> 5) * 64 + ((l & 15) >> 2) * 16 +
                     (((l >> 4) & 1) * 4 + (l & 3)) * 2;
  int stb[8];
#pragma unroll
  for (int j = 0; j < 8; ++j)
    stb[j] = w * 1024 + j * 128 + (innerL ^ (j << 4));

  const int krow = w * 8 + (l >> 3);
  const int kseg = (l & 7) ^ (krow & 7);
  const bf16* kP = K + base + (size_t)krow * HD + kseg * 8;
  const bf16* vP = Vh + (size_t)l * HD + w * 8;

  f32x4 yacc[4] = {};
  float m_ = -1e30f, l_ = 0.f;
  const int nt = 2 * qtile + 2;
  const int it_mask = 2 * qtile + (w >= 4 ? 1 : 0);
  const int diag = (w & 3) * 16 + q16;

#define STAGE_K(KBUF)                           \
  {                                             \
    gl_lds16(kP, smem + (KBUF) + w * 1024);     \
    kP += 4096;                                 \
  }
#define WRITE_V(VBUF, a0)                               \
  {                                                     \
    _Pragma("unroll") for (int j = 0; j < 8; ++j)       \
      *(bf16*)(smem + (VBUF) + stb[j]) = a0[j];         \
  }
#define COMPUTE(KBUF, VBUF, DOMASK)                                          \
  {                                                                          \
    f32x4 s[4] = {};                                                         \
    __builtin_amdgcn_s_setprio(1);                                           \
    _Pragma("unroll") for (int nj = 0; nj < 4; ++nj) {                       \
      bf16x8 ak0 = *(const bf16x8*)(smem + (KBUF) + qkB0 + nj * 2048);       \
      s[nj] = __builtin_amdgcn_mfma_f32_16x16x32_bf16(ak0, aq[0], s[nj], 0, 0, 0); \
      bf16x8 ak1 = *(const bf16x8*)(smem + (KBUF) + qkB1 + nj * 2048);       \
      s[nj] = __builtin_amdgcn_mfma_f32_16x16x32_bf16(ak1, aq[1], s[nj], 0, 0, 0); \
    }                                                                        \
    __builtin_amdgcn_s_setprio(0);                                           \
    if (DOMASK) {                                                            \
      _Pragma("unroll") for (int nj = 0; nj < 4; ++nj)                       \
        _Pragma("unroll") for (int r = 0; r < 4; ++r)                        \
          if (nj * 16 + g * 4 + r > diag) s[nj][r] = -1e30f;                 \
    }                                                                        \
    float mx = fmaxf(fmaxf(fmaxf(s[0][0], s[0][1]), fmaxf(s[0][2], s[0][3])),\
                     fmaxf(fmaxf(s[1][0], s[1][1]), fmaxf(s[1][2], s[1][3])));\
    mx = fmaxf(mx, fmaxf(fmaxf(fmaxf(s[2][0], s[2][1]), fmaxf(s[2][2], s[2][3])),\
                         fmaxf(fmaxf(s[3][0], s[3][1]), fmaxf(s[3][2], s[3][3]))));\
    mx = fmaxf(mx, __shfl_xor(mx, 16));                                      \
    mx = fmaxf(mx, __shfl_xor(mx, 32));                                      \
    if (!__all(mx <= m_ + 8.f)) { /* T13 defer-max */                        \
      float mn = fmaxf(m_, mx);                                              \
      float fac = __builtin_amdgcn_exp2f(m_ - mn);                           \
      m_ = mn;                                                               \
      l_ *= fac;                                                             \
      _Pragma("unroll") for (int ni = 0; ni < 4; ++ni)                       \
        _Pragma("unroll") for (int r = 0; r < 4; ++r) yacc[ni][r] *= fac;    \
    }                                                                        \
    float rs = 0.f;                                                          \
    _Pragma("unroll") for (int nj = 0; nj < 4; ++nj)                         \
      _Pragma("unroll") for (int r = 0; r < 4; ++r) {                        \
        float pv = __builtin_amdgcn_exp2f(s[nj][r] - m_);                    \
        s[nj][r] = pv;                                                       \
        rs += pv;                                                            \
      }                                                                      \
    rs += __shfl_xor(rs, 16);                                                \
    rs += __shfl_xor(rs, 32);                                                \
    l_ += rs;                                                                \
    __builtin_amdgcn_s_setprio(1);                                           \
    _Pragma("unroll") for (int vkc = 0; vkc < 2; ++vkc) {                    \
      bf16x8 pb;                                                             \
      _Pragma("unroll") for (int j = 0; j < 4; ++j) {                        \
        pb[j] = (bf16)s[2 * vkc][j];                                         \
        pb[4 + j] = (bf16)s[2 * vkc + 1][j];                                 \
      }                                                                      \
      int vb = (vkc == 0) ? qkB0 : qkB1;                                     \
      _Pragma("unroll") for (int ni = 0; ni < 4; ++ni) {                     \
        bf16x8 va = *(const bf16x8*)(smem + (VBUF) + vb + ni * 2048);        \
        yacc[ni] = __builtin_amdgcn_mfma_f32_16x16x32_bf16(va, pb, yacc[ni], 0, 0, 0); \
      }                                                                      \
    }                                                                        \
    __builtin_amdgcn_s_setprio(0);                                           \
  }

  STAGE_K(0);
  {
    bf16x8 a0 = *(const bf16x8*)vP;
    vP += 4096;
    WRITE_V(16384, a0);
  }

  int it = 0;
  for (;;) {
    __syncthreads();
    bool more = (it + 1) < nt;
    bf16x8 a0;
    if (more) {
      STAGE_K(8192);
      a0 = *(const bf16x8*)vP;
      vP += 4096;
    }
    if (it <= it_mask) COMPUTE(0, 16384, it == it_mask);
    if (more) WRITE_V(24576, a0);
    if (++it >= nt) break;

    __syncthreads();
    more = (it + 1) < nt;
    if (more) {
      STAGE_K(0);
      a0 = *(const bf16x8*)vP;
      vP += 4096;
    }
    if (it <= it_mask) COMPUTE(8192, 24576, it == it_mask);
    if (more) WRITE_V(16384, a0);
    if (++it >= nt) break;
  }
#undef STAGE_K
#undef WRITE_V
#undef COMPUTE

  const int hh = bh & 15, bb = bh >> 4;
  float inv = 1.f / l_;
#pragma unroll
  for (int ni = 0; ni < 4; ++ni) {
    bf16x4 o;
#pragma unroll
    for (int r = 0; r < 4; ++r) o[r] = (bf16)(yacc[ni][r] * inv);
    int d0 = ni * 16 + g * 4;
    *(bf16x4*)&Y[(size_t)(bb * Tn + qg) * Cn + hh * HD + d0] = o;
  }
}

extern "C" void kernel_launch(void* const* d_in, const int* in_sizes, int n_in,
                              void* d_out, int out_size, void* d_ws,
                              size_t ws_size, hipStream_t stream) {
  const float* x  = (const float*)d_in[0];
  const float* Wq = (const float*)d_in[1];
  const float* bq = (const float*)d_in[2];
  const float* Wk = (const float*)d_in[3];
  const float* bk = (const float*)d_in[4];
  const float* Wv = (const float*)d_in[5];
  const float* bv = (const float*)d_in[6];
  const float* Wo = (const float*)d_in[7];
  const float* bo = (const float*)d_in[8];
  char* ws = (char*)d_ws;
  bf16* xb = (bf16*)ws;                          // 16MB, reused as y
  bf16* WT = (bf16*)(ws + (size_t)(16 << 20));   // 8MB (4 x 1M elems)
  bf16* Qh = (bf16*)(ws + (size_t)(24 << 20));   // 16MB (K,V follow)
  bf16* Kh = (bf16*)(ws + (size_t)(40 << 20));
  bf16* Vh = (bf16*)(ws + (size_t)(56 << 20));
  float* out = (float*)d_out;                    // reference output is fp32

  const float QSCALE = 0.125f * 1.44269504088896f;  // 1/sqrt(64) * log2(e)

  k_prep<<<8192, 256, 0, stream>>>(x, xb, Wq, Wk, Wv, Wo, WT);
  k_gemm_qkv8<<<1536, 512, 0, stream>>>(xb, WT, bq, bk, bv, Qh, QSCALE);
  k_attn<<<1024, 512, 0, stream>>>(Qh, Kh, Vh, xb);
  k_gemm_o8<<<512, 512, 0, stream>>>(xb, WT + (3u << 20), bo, out);
}